// Round 2
// baseline (186.928 us; speedup 1.0000x reference)
//
#include <hip/hip_runtime.h>

#define BATCH 4
#define SEQ   4096
#define CDIM  1024
#define DDIM  64
#define NROW  (BATCH * SEQ)   // 16384
#define NSPL  8               // attn key-split
#define SEG   (NROW * DDIM)   // 1M elements per q/k/v buffer

typedef _Float16 f16;
typedef _Float16 f16x8 __attribute__((ext_vector_type(8)));
typedef _Float16 f16x4 __attribute__((ext_vector_type(4)));
typedef __fp16   h16x2 __attribute__((ext_vector_type(2)));  // cvt_pkrtz return type
typedef float    f32x4 __attribute__((ext_vector_type(4)));

#define MFMA32(a, b, c) __builtin_amdgcn_mfma_f32_16x16x32_f16((a), (b), (c), 0, 0, 0)
#define MFMA16(a, b, c) __builtin_amdgcn_mfma_f32_16x16x16f16((a), (b), (c), 0, 0, 0)

// async global->LDS DMA, 16 B per lane; LDS dest = wave-uniform base + lane*16
#define GLDS(g, l)                                                            \
  __builtin_amdgcn_global_load_lds((const __attribute__((address_space(1))) void*)(g), \
                                   (__attribute__((address_space(3))) void*)(l), 16, 0, 0)

// scores = (q·k)*8 (the /scale bug); softmax in exp2 domain => fold 8*log2(e) into q
#define QSCALE 11.5415603f

__device__ inline f16x8 cvt8(f32x4 a, f32x4 b) {
  h16x2 p0 = __builtin_amdgcn_cvt_pkrtz(a[0], a[1]);
  h16x2 p1 = __builtin_amdgcn_cvt_pkrtz(a[2], a[3]);
  h16x2 p2 = __builtin_amdgcn_cvt_pkrtz(b[0], b[1]);
  h16x2 p3 = __builtin_amdgcn_cvt_pkrtz(b[2], b[3]);
  f16x8 r;
  r[0] = p0[0]; r[1] = p0[1]; r[2] = p1[0]; r[3] = p1[1];
  r[4] = p2[0]; r[5] = p2[1]; r[6] = p3[0]; r[7] = p3[1];
  return r;
}

__device__ inline f16x4 cvt4(float a, float b, float c, float d) {
  h16x2 lo = __builtin_amdgcn_cvt_pkrtz(a, b);
  h16x2 hi = __builtin_amdgcn_cvt_pkrtz(c, d);
  f16x4 r;
  r[0] = lo[0]; r[1] = lo[1]; r[2] = hi[0]; r[3] = hi[1];
  return r;
}

// ---------------- W prep: fp32 -> f16, shuffled into per-chunk DMA order ------
// wf2 slot s = ck*12 + mt (ck 0..31 = 32-ch chunk, mt = mat*4+tile), 512 f16.
__global__ __launch_bounds__(256) void prep_w_kernel(const float* __restrict__ Wq,
                                                     const float* __restrict__ Wk,
                                                     const float* __restrict__ Wv,
                                                     f16* __restrict__ wf2) {
  const int t = blockIdx.x * 256 + threadIdx.x;  // 96 blocks -> 24576 threads
  const int lane = t & 63;
  const int s = t >> 6;                // 0..383
  const int mt = s % 12, ck = s / 12;
  const int mat = mt >> 2, tile = mt & 3;
  const int n = lane & 15, quad = lane >> 4;
  const float* W = (mat == 0) ? Wq : (mat == 1) ? Wk : Wv;
  const float* src = W + (size_t)(tile * 16 + n) * CDIM + ck * 32 + quad * 8;
  const f32x4 a = *(const f32x4*)src;
  const f32x4 b = *(const f32x4*)(src + 4);
  *(f16x8*)(wf2 + (size_t)t * 8) = cvt8(a, b);
}

// ---------------- fused QKV projection: full-K direct, no partials -----------
// 512 blocks x 512 thr (8 waves); 32 rows/block, full 1024 ch in 32 chunks of
// 32. LDS dbuf 2x16 KB (x 4K | w 12K) -> 2 blocks/CU = 16 issuing waves (same
// concurrency as old KS=4 layout). Wave w: row-tile (w>>2), mt = 3*(w&3)..+2,
// 3 MFMA32/chunk. Epilogue adds bias (+QSCALE for q) and writes qs (plain),
// ks (col-swizzled), vc (chunk-major swizzled tiles) DIRECTLY -- eliminates
// the 24 MB ppart write + 24 MB re-read + combine_proj kernel entirely.
// x LDS A-frag read de-conflicted: source pre-swizzled (16B-chunk ^= row&7,
// linear GLDS dest), read XORs the same involution.
__global__ __launch_bounds__(512, 4) void proj_kernel(const float* __restrict__ x,
                                                      const f16* __restrict__ wf2,
                                                      const float* __restrict__ bq,
                                                      const float* __restrict__ bk,
                                                      const float* __restrict__ bv,
                                                      f16* __restrict__ qs,
                                                      f16* __restrict__ ks,
                                                      f16* __restrict__ vc) {
  __shared__ __attribute__((aligned(16))) char smem[2][16384];  // [x 4K | w 12K]
  const int tid = threadIdx.x, lane = tid & 63, w = tid >> 6;   // w 0..7
  const int n = lane & 15, quad = lane >> 4;
  const int rowbase = blockIdx.x * 32;

  // DMA: 16 wave-instrs/chunk (4 x + 12 W); wave w issues 2.
  const float* xsrc[2] = {nullptr, nullptr};
  const f16* wsrc[2] = {nullptr, nullptr};
  int xdst[2] = {0, 0}, wdst[2] = {0, 0};
  if (w < 2) {
#pragma unroll
    for (int j = 0; j < 2; ++j) {
      const int i = 2 * w + j;  // x instr 0..3, rows i*8..i*8+8 (128 B/row/chunk)
      // source chunk-swizzle: 16B chunk (lane&7) ^ (row&7), row = lane>>3 (i*8 = 0 mod 8)
      xsrc[j] = x + (size_t)(rowbase + i * 8 + (lane >> 3)) * CDIM +
                (((lane & 7) ^ ((lane >> 3) & 7)) * 4);
      xdst[j] = i * 1024;
    }
  } else {
#pragma unroll
    for (int j = 0; j < 2; ++j) {
      const int mt = 2 * (w - 2) + j;  // 0..11
      wsrc[j] = wf2 + (size_t)mt * 512 + lane * 8;  // +ck*12*512 per chunk
      wdst[j] = 4096 + mt * 1024;
    }
  }

  auto issue = [&](int ck, int b) {
    char* base = &smem[b][0];
    if (w < 2) {
#pragma unroll
      for (int j = 0; j < 2; ++j) GLDS(xsrc[j] + ck * 32, base + xdst[j]);
    } else {
#pragma unroll
      for (int j = 0; j < 2; ++j) GLDS(wsrc[j] + (size_t)ck * 6144, base + wdst[j]);
    }
  };

  const int rt = w >> 2, mtb = 3 * (w & 3);
  f32x4 acc[3];
#pragma unroll
  for (int i = 0; i < 3; ++i) acc[i] = (f32x4){0.f, 0.f, 0.f, 0.f};

  issue(0, 0);
  for (int ck = 0; ck < 32; ++ck) {
    const int b = ck & 1;
    __syncthreads();                       // drains chunk ck's DMA
    if (ck + 1 < 32) issue(ck + 1, b ^ 1); // in flight across compute
    const char* base = &smem[b][0];
    // A-frag: row = rt*16+n, k = quad*8+j; swizzled 16B-chunk read (row&7 = n&7)
    const char* xb = base + (rt * 16 + n) * 128;
    const f32x4 xa = *(const f32x4*)(xb + ((((quad << 1) ^ (n & 7)) << 4)));
    const f32x4 xc = *(const f32x4*)(xb + (((((quad << 1) | 1) ^ (n & 7)) << 4)));
    const f16x8 a = cvt8(xa, xc);
#pragma unroll
    for (int i2 = 0; i2 < 3; ++i2) {
      const f16x8 bf = *(const f16x8*)(base + 4096 + (mtb + i2) * 1024 + lane * 16);
      acc[i2] = MFMA32(a, bf, acc[i2]);
    }
  }

  // epilogue: bias + final layouts (q plain*QSCALE, k swizzled, v tiles)
  const int r0 = rowbase + rt * 16 + quad * 4;
#pragma unroll
  for (int i2 = 0; i2 < 3; ++i2) {
    const int mt = mtb + i2;
    const int mat = mt >> 2, tile = mt & 3;
    const int d = tile * 16 + n;  // d&15 == n
    const f32x4 aa = acc[i2];
    if (mat == 0) {
      const float bi = bq[d];
#pragma unroll
      for (int r = 0; r < 4; ++r)
        qs[(size_t)(r0 + r) * DDIM + d] = (f16)((aa[r] + bi) * QSCALE);
    } else if (mat == 1) {
      const float bi = bk[d];
#pragma unroll
      for (int r = 0; r < 4; ++r) {
        const int t = r0 + r;
        const int col = ((((d >> 3) ^ (t & 7)) << 3) | (d & 7));
        ks[(size_t)t * DDIM + col] = (f16)(aa[r] + bi);
      }
    } else {
      const float bi = bv[d];
      const int bb = r0 >> 12;
      const int tl = r0 & (SEQ - 1);
      const int ck2 = tl >> 6;
      const int bsw = (((tl & 63) >> 2) ^ n) << 2;
      *(f16x4*)(vc + ((size_t)(bb * 64 + ck2) * 64 + d) * 64 + bsw) =
          cvt4(aa[0] + bi, aa[1] + bi, aa[2] + bi, aa[3] + bi);
    }
  }
}

// ---------------- flash attention: DMA-staged K/V, dbuf, 1 barrier/chunk ------
// S' = K·Q^T (C-layout row=key, col=q), per-lane softmax, P stays in registers
// as 16x16x16 B-fragments. K/V tiles DMA'd contiguously (8 KB each) into
// unpadded LDS; swizzled global layouts make fragment reads phase-optimal.
template <int NSPLIT>
__global__ __launch_bounds__(256, 4) void attn_kernel(const f16* __restrict__ qs,
                                                      const f16* __restrict__ ks,
                                                      const f16* __restrict__ vc,
                                                      float* __restrict__ outp,
                                                      f16* __restrict__ pacc,
                                                      float* __restrict__ pm,
                                                      float* __restrict__ pl) {
  __shared__ __attribute__((aligned(16))) f16 lk[2][4096];  // [buf][key][64 d swz]
  __shared__ __attribute__((aligned(16))) f16 lv[2][4096];  // [buf][d][64 key swz]
  const int tid = threadIdx.x, lane = tid & 63, w = tid >> 6;
  const int n = lane & 15, quad = lane >> 4;
  const int split = blockIdx.x % NSPLIT;
  const int rowblk = blockIdx.x / NSPLIT;
  const int row0 = rowblk * 128 + w * 32;
  const int bb = row0 >> 12;
  const int kbase = split * (SEQ / NSPLIT);
  const int kc0 = kbase >> 6;
  const int NC = SEQ / NSPLIT / 64;

  const f16* ksb = ks + (size_t)bb * SEQ * DDIM;
  const f16* vcb = vc + (size_t)bb * 64 * 4096;

  auto issue = [&](int c, int buf) {
#pragma unroll
    for (int i = 0; i < 2; ++i) {
      const int id = 2 * w + i;
      GLDS(ksb + (size_t)(kbase + c * 64) * 64 + id * 512 + lane * 8, &lk[buf][id * 512]);
      GLDS(vcb + (size_t)(kc0 + c) * 4096 + id * 512 + lane * 8, &lv[buf][id * 512]);
    }
  };

  // persistent Q B-fragments (16x16x32): B[k=d=quad*8+j][col=q=n]
  f16x8 qf[2][2];
#pragma unroll
  for (int g = 0; g < 2; ++g)
#pragma unroll
    for (int hh = 0; hh < 2; ++hh)
      qf[g][hh] = *(const f16x8*)(qs + (size_t)(row0 + g * 16 + n) * DDIM + hh * 32 + quad * 8);

  // swizzle read offsets (per-lane constants)
  const int kswz = (quad ^ (n & 7)) << 3;          // klo block; khi = kswz ^ 32
  int vswz[4];
#pragma unroll
  for (int st = 0; st < 4; ++st) vswz[st] = ((((st << 2) | quad) ^ n) << 2);

  f32x4 acc[2][4];
  float m[2] = {-1e30f, -1e30f}, ll[2] = {0.f, 0.f};
#pragma unroll
  for (int g = 0; g < 2; ++g)
#pragma unroll
    for (int t = 0; t < 4; ++t) acc[g][t] = (f32x4){0.f, 0.f, 0.f, 0.f};

  issue(0, 0);
  for (int c = 0; c < NC; ++c) {
    const int b = c & 1;
    __syncthreads();                      // drains chunk c's DMA; guards buffers
    if (c + 1 < NC) issue(c + 1, b ^ 1);  // in flight across entire compute phase

    // S' = K·Q^T
    f32x4 s[2][4];
#pragma unroll
    for (int st = 0; st < 4; ++st) {
      const f16* lkr = &lk[b][(st * 16 + n) * 64];
      const f16x8 klo = *(const f16x8*)(lkr + kswz);
      const f16x8 khi = *(const f16x8*)(lkr + (kswz ^ 32));
#pragma unroll
      for (int g = 0; g < 2; ++g) {
        f32x4 z = (f32x4){0.f, 0.f, 0.f, 0.f};
        z = MFMA32(klo, qf[g][0], z);
        s[g][st] = MFMA32(khi, qf[g][1], z);
      }
    }

    // per-lane online softmax; P packed directly as 16x16x16 B-fragments
    f16x4 pq[2][4];
#pragma unroll
    for (int g = 0; g < 2; ++g) {
      f32x4 mx;
#pragma unroll
      for (int r = 0; r < 4; ++r)
        mx[r] = fmaxf(fmaxf(s[g][0][r], s[g][1][r]), fmaxf(s[g][2][r], s[g][3][r]));
      float mloc = fmaxf(fmaxf(mx[0], mx[1]), fmaxf(mx[2], mx[3]));
      mloc = fmaxf(mloc, __shfl_xor(mloc, 16));
      mloc = fmaxf(mloc, __shfl_xor(mloc, 32));
      const float mnew = fmaxf(m[g], mloc);
      const float alpha = __builtin_amdgcn_exp2f(m[g] - mnew);
      m[g] = mnew;
      float psum = 0.f;
#pragma unroll
      for (int st = 0; st < 4; ++st) {
        f32x4 p;
#pragma unroll
        for (int r = 0; r < 4; ++r) p[r] = __builtin_amdgcn_exp2f(s[g][st][r] - mnew);
        psum += (p[0] + p[1]) + (p[2] + p[3]);
        pq[g][st] = cvt4(p[0], p[1], p[2], p[3]);
      }
      ll[g] = ll[g] * alpha + psum;
#pragma unroll
      for (int t = 0; t < 4; ++t) acc[g][t] *= alpha;
    }

    // O^T += V^T·P^T : A = V^T frag [m=d][k=key quad*4+j] (swizzled LDS read)
#pragma unroll
    for (int dt = 0; dt < 4; ++dt) {
      const f16* lvr = &lv[b][(dt * 16 + n) * 64];
#pragma unroll
      for (int st = 0; st < 4; ++st) {
        const f16x4 va = *(const f16x4*)(lvr + vswz[st]);
        acc[0][dt] = MFMA16(va, pq[0][st], acc[0][dt]);
        acc[1][dt] = MFMA16(va, pq[1][st], acc[1][dt]);
      }
    }
  }

  float lred[2];
#pragma unroll
  for (int g = 0; g < 2; ++g) {
    float l = ll[g];
    l += __shfl_xor(l, 16);
    l += __shfl_xor(l, 32);
    lred[g] = l;
  }

  if (NSPLIT == 1) {
#pragma unroll
    for (int g = 0; g < 2; ++g) {
      const float inv = 1.0f / lred[g];
      const int q = row0 + g * 16 + n;
#pragma unroll
      for (int t = 0; t < 4; ++t) {
        f32x4 o = acc[g][t];
#pragma unroll
        for (int r = 0; r < 4; ++r) o[r] *= inv;
        *(f32x4*)(outp + (size_t)q * DDIM + t * 16 + quad * 4) = o;
      }
    }
  } else {
#pragma unroll
    for (int g = 0; g < 2; ++g) {
      const int q = row0 + g * 16 + n;
#pragma unroll
      for (int t = 0; t < 4; ++t)
        *(f16x4*)(pacc + ((size_t)split * NROW + q) * DDIM + t * 16 + quad * 4) =
            cvt4(acc[g][t][0], acc[g][t][1], acc[g][t][2], acc[g][t][3]);
      if (quad == 0) {
        pm[split * NROW + q] = m[g];
        pl[split * NROW + q] = lred[g];
      }
    }
  }
}

// ---------------- attn split-K combine (f16 partials) ----------------
template <int NSPLIT>
__global__ __launch_bounds__(256) void combine_kernel(const f16* __restrict__ pacc,
                                                      const float* __restrict__ pm,
                                                      const float* __restrict__ pl,
                                                      float* __restrict__ out) {
  const int idx = blockIdx.x * 256 + threadIdx.x;  // NROW*16 units
  const int row = idx >> 4;
  const int c = (idx & 15) * 4;
  float mm = pm[row];
#pragma unroll
  for (int s = 1; s < NSPLIT; ++s) mm = fmaxf(mm, pm[s * NROW + row]);
  float L = 0.f;
  f32x4 o = (f32x4){0.f, 0.f, 0.f, 0.f};
#pragma unroll
  for (int s = 0; s < NSPLIT; ++s) {
    const float e = __builtin_amdgcn_exp2f(pm[s * NROW + row] - mm);
    L += pl[s * NROW + row] * e;
    const f16x4 a = *(const f16x4*)(pacc + ((size_t)s * NROW + row) * DDIM + c);
#pragma unroll
    for (int j = 0; j < 4; ++j) o[j] += (float)a[j] * e;
  }
  const float inv = 1.0f / L;
#pragma unroll
  for (int j = 0; j < 4; ++j) o[j] *= inv;
  *(f32x4*)(out + (size_t)row * DDIM + c) = o;
}

extern "C" void kernel_launch(void* const* d_in, const int* in_sizes, int n_in,
                              void* d_out, int out_size, void* d_ws, size_t ws_size,
                              hipStream_t stream) {
  const float* x  = (const float*)d_in[0];
  const float* Wq = (const float*)d_in[1];
  const float* bq = (const float*)d_in[2];
  const float* Wk = (const float*)d_in[3];
  const float* bk = (const float*)d_in[4];
  const float* Wv = (const float*)d_in[5];
  const float* bv = (const float*)d_in[6];
  float* out = (float*)d_out;

  f16* wf2 = (f16*)d_ws;                      // 3*64*1024 f16, chunk-slot layout
  f16* qs = wf2 + 3 * 65536;
  f16* ks = qs + (size_t)SEG;                 // block-swizzled
  f16* vc = ks + (size_t)SEG;                 // chunk-major tiles, swizzled
  f16* pacc = vc + (size_t)SEG;               // [NSPL][NROW][64] f16 attn partials
  float* pm = (float*)(pacc + (size_t)NSPL * SEG);
  float* pl = pm + (size_t)NSPL * NROW;
  const size_t need = (size_t)((char*)(pl + (size_t)NSPL * NROW) - (char*)d_ws);

  prep_w_kernel<<<dim3(96), dim3(256), 0, stream>>>(Wq, Wk, Wv, wf2);
  proj_kernel<<<dim3(512), dim3(512), 0, stream>>>(x, wf2, bq, bk, bv, qs, ks, vc);

  if (ws_size >= need) {
    attn_kernel<NSPL><<<dim3(128 * NSPL), dim3(256), 0, stream>>>(qs, ks, vc, nullptr, pacc, pm, pl);
    combine_kernel<NSPL><<<dim3(NROW * 16 / 256), dim3(256), 0, stream>>>(pacc, pm, pl, out);
  } else {
    attn_kernel<1><<<dim3(128), dim3(256), 0, stream>>>(qs, ks, vc, out, nullptr, nullptr, nullptr);
  }
}

// Round 3
// 171.719 us; speedup vs baseline: 1.0886x; 1.0886x over previous
//
#include <hip/hip_runtime.h>

#define BATCH 4
#define SEQ   4096
#define CDIM  1024
#define DDIM  64
#define NROW  (BATCH * SEQ)   // 16384
#define NSPL  8               // attn key-split
#define SEG   (NROW * DDIM)   // 1M elements per q/k/v buffer

typedef _Float16 f16;
typedef _Float16 f16x8 __attribute__((ext_vector_type(8)));
typedef _Float16 f16x4 __attribute__((ext_vector_type(4)));
typedef __fp16   h16x2 __attribute__((ext_vector_type(2)));  // cvt_pkrtz return type
typedef float    f32x4 __attribute__((ext_vector_type(4)));

#define MFMA32(a, b, c) __builtin_amdgcn_mfma_f32_16x16x32_f16((a), (b), (c), 0, 0, 0)
#define MFMA16(a, b, c) __builtin_amdgcn_mfma_f32_16x16x16f16((a), (b), (c), 0, 0, 0)

// async global->LDS DMA, 16 B per lane; LDS dest = wave-uniform base + lane*16
#define GLDS(g, l)                                                            \
  __builtin_amdgcn_global_load_lds((const __attribute__((address_space(1))) void*)(g), \
                                   (__attribute__((address_space(3))) void*)(l), 16, 0, 0)

// scores = (q·k)*8 (the /scale bug); softmax in exp2 domain => fold 8*log2(e) into q
#define QSCALE 11.5415603f

__device__ inline f16x8 cvt8(f32x4 a, f32x4 b) {
  h16x2 p0 = __builtin_amdgcn_cvt_pkrtz(a[0], a[1]);
  h16x2 p1 = __builtin_amdgcn_cvt_pkrtz(a[2], a[3]);
  h16x2 p2 = __builtin_amdgcn_cvt_pkrtz(b[0], b[1]);
  h16x2 p3 = __builtin_amdgcn_cvt_pkrtz(b[2], b[3]);
  f16x8 r;
  r[0] = p0[0]; r[1] = p0[1]; r[2] = p1[0]; r[3] = p1[1];
  r[4] = p2[0]; r[5] = p2[1]; r[6] = p3[0]; r[7] = p3[1];
  return r;
}

__device__ inline f16x4 cvt4(float a, float b, float c, float d) {
  h16x2 lo = __builtin_amdgcn_cvt_pkrtz(a, b);
  h16x2 hi = __builtin_amdgcn_cvt_pkrtz(c, d);
  f16x4 r;
  r[0] = lo[0]; r[1] = lo[1]; r[2] = hi[0]; r[3] = hi[1];
  return r;
}

// ---------------- W prep: fp32 -> f16, shuffled into per-chunk fragment order -
// wf2 slot s = ck*12 + mt (ck 0..31 = 32-ch chunk, mt = mat*4+tile), 512 f16.
// Lane l of slot s holds B-frag bytes l*16: W[tile*16+n][ck*32+quad*8+j].
__global__ __launch_bounds__(256) void prep_w_kernel(const float* __restrict__ Wq,
                                                     const float* __restrict__ Wk,
                                                     const float* __restrict__ Wv,
                                                     f16* __restrict__ wf2) {
  const int t = blockIdx.x * 256 + threadIdx.x;  // 96 blocks -> 24576 threads
  const int lane = t & 63;
  const int s = t >> 6;                // 0..383
  const int mt = s % 12, ck = s / 12;
  const int mat = mt >> 2, tile = mt & 3;
  const int n = lane & 15, quad = lane >> 4;
  const float* W = (mat == 0) ? Wq : (mat == 1) ? Wk : Wv;
  const float* src = W + (size_t)(tile * 16 + n) * CDIM + ck * 32 + quad * 8;
  const f32x4 a = *(const f32x4*)src;
  const f32x4 b = *(const f32x4*)(src + 4);
  *(f16x8*)(wf2 + (size_t)t * 8) = cvt8(a, b);
}

// ---------------- fused QKV projection: register-pipelined, NO LDS/barriers --
// Round-2 post-mortem: barrier-per-chunk + global_load_lds serialized on the
// vmcnt(0) drain (MfmaUtil 3.4%, all pipes idle). Fix: fragments load straight
// to registers. W frags are 1 KB coalesced loads from L2-resident wf2 (384 KB);
// x frags are each lane's own 32 contiguous bytes. Manual 2-chunk double buffer
// with NAMED registers (rule #20) -> compiler emits counted vmcnt, loads stay
// in flight across chunks, zero sync. Wave = 32 rows x 3 mt-tiles; block = 4
// waves sharing the same 32 x-rows (L1 dedup). 512 blocks x 256 thr = 8
// waves/CU, each with ~7-14 outstanding loads.
__global__ __launch_bounds__(256) void proj_kernel(const float* __restrict__ x,
                                                   const f16* __restrict__ wf2,
                                                   const float* __restrict__ bq,
                                                   const float* __restrict__ bk,
                                                   const float* __restrict__ bv,
                                                   f16* __restrict__ qs,
                                                   f16* __restrict__ ks,
                                                   f16* __restrict__ vc) {
  const int tid = threadIdx.x, lane = tid & 63, w = tid >> 6;  // w 0..3
  const int n = lane & 15, quad = lane >> 4;
  const int rowbase = blockIdx.x * 32;
  const int mtb = 3 * w;

  // per-lane global bases
  const float* xp0 = x + (size_t)(rowbase + n) * CDIM + quad * 8;       // row-tile 0
  const float* xp1 = x + (size_t)(rowbase + 16 + n) * CDIM + quad * 8;  // row-tile 1
  const f16* wp = wf2 + (size_t)mtb * 512 + lane * 8;                   // + ck*6144

  f32x4 acc[6];  // [t*3 + i2], all indices compile-time after unroll
#pragma unroll
  for (int i = 0; i < 6; ++i) acc[i] = (f32x4){0.f, 0.f, 0.f, 0.f};

#define LOADCK(ck, A0, C0, A1, C1, W0, W1, W2)                  \
  do {                                                          \
    const float* xq0 = xp0 + (ck) * 32;                         \
    const float* xq1 = xp1 + (ck) * 32;                         \
    A0 = *(const f32x4*)xq0; C0 = *(const f32x4*)(xq0 + 4);     \
    A1 = *(const f32x4*)xq1; C1 = *(const f32x4*)(xq1 + 4);     \
    const f16* wq = wp + (size_t)(ck) * 6144;                   \
    W0 = *(const f16x8*)(wq);                                   \
    W1 = *(const f16x8*)(wq + 512);                             \
    W2 = *(const f16x8*)(wq + 1024);                            \
  } while (0)

#define COMPCK(A0, C0, A1, C1, W0, W1, W2)                      \
  do {                                                          \
    const f16x8 fa0 = cvt8(A0, C0);                             \
    const f16x8 fa1 = cvt8(A1, C1);                             \
    acc[0] = MFMA32(fa0, W0, acc[0]);                           \
    acc[3] = MFMA32(fa1, W0, acc[3]);                           \
    acc[1] = MFMA32(fa0, W1, acc[1]);                           \
    acc[4] = MFMA32(fa1, W1, acc[4]);                           \
    acc[2] = MFMA32(fa0, W2, acc[2]);                           \
    acc[5] = MFMA32(fa1, W2, acc[5]);                           \
  } while (0)

  f32x4 a0, c0, a1, c1, b0, d0, b1, d1;
  f16x8 u0, u1, u2, v0, v1, v2;
  LOADCK(0, a0, c0, a1, c1, u0, u1, u2);
  for (int ck = 0; ck < 32; ck += 2) {
    LOADCK(ck + 1, b0, d0, b1, d1, v0, v1, v2);
    COMPCK(a0, c0, a1, c1, u0, u1, u2);
    if (ck + 2 < 32) LOADCK(ck + 2, a0, c0, a1, c1, u0, u1, u2);
    COMPCK(b0, d0, b1, d1, v0, v1, v2);
  }
#undef LOADCK
#undef COMPCK

  // epilogue: bias + final layouts (q plain*QSCALE, k swizzled, v tiles)
#pragma unroll
  for (int t = 0; t < 2; ++t) {
    const int r0 = rowbase + t * 16 + quad * 4;
#pragma unroll
    for (int i2 = 0; i2 < 3; ++i2) {
      const int mt = mtb + i2;
      const int mat = mt >> 2, tile = mt & 3;
      const int d = tile * 16 + n;  // d&15 == n
      const f32x4 aa = acc[t * 3 + i2];
      if (mat == 0) {
        const float bi = bq[d];
#pragma unroll
        for (int r = 0; r < 4; ++r)
          qs[(size_t)(r0 + r) * DDIM + d] = (f16)((aa[r] + bi) * QSCALE);
      } else if (mat == 1) {
        const float bi = bk[d];
#pragma unroll
        for (int r = 0; r < 4; ++r) {
          const int tt = r0 + r;
          const int col = ((((d >> 3) ^ (tt & 7)) << 3) | (d & 7));
          ks[(size_t)tt * DDIM + col] = (f16)(aa[r] + bi);
        }
      } else {
        const float bi = bv[d];
        const int bb = r0 >> 12;
        const int tl = r0 & (SEQ - 1);
        const int ck2 = tl >> 6;
        const int bsw = (((tl & 63) >> 2) ^ n) << 2;
        *(f16x4*)(vc + ((size_t)(bb * 64 + ck2) * 64 + d) * 64 + bsw) =
            cvt4(aa[0] + bi, aa[1] + bi, aa[2] + bi, aa[3] + bi);
      }
    }
  }
}

// ---------------- flash attention: DMA-staged K/V, dbuf, 1 barrier/chunk ------
// S' = K·Q^T (C-layout row=key, col=q), per-lane softmax, P stays in registers
// as 16x16x16 B-fragments. K/V tiles DMA'd contiguously (8 KB each) into
// unpadded LDS; swizzled global layouts make fragment reads phase-optimal.
template <int NSPLIT>
__global__ __launch_bounds__(256, 4) void attn_kernel(const f16* __restrict__ qs,
                                                      const f16* __restrict__ ks,
                                                      const f16* __restrict__ vc,
                                                      float* __restrict__ outp,
                                                      f16* __restrict__ pacc,
                                                      float* __restrict__ pm,
                                                      float* __restrict__ pl) {
  __shared__ __attribute__((aligned(16))) f16 lk[2][4096];  // [buf][key][64 d swz]
  __shared__ __attribute__((aligned(16))) f16 lv[2][4096];  // [buf][d][64 key swz]
  const int tid = threadIdx.x, lane = tid & 63, w = tid >> 6;
  const int n = lane & 15, quad = lane >> 4;
  const int split = blockIdx.x % NSPLIT;
  const int rowblk = blockIdx.x / NSPLIT;
  const int row0 = rowblk * 128 + w * 32;
  const int bb = row0 >> 12;
  const int kbase = split * (SEQ / NSPLIT);
  const int kc0 = kbase >> 6;
  const int NC = SEQ / NSPLIT / 64;

  const f16* ksb = ks + (size_t)bb * SEQ * DDIM;
  const f16* vcb = vc + (size_t)bb * 64 * 4096;

  auto issue = [&](int c, int buf) {
#pragma unroll
    for (int i = 0; i < 2; ++i) {
      const int id = 2 * w + i;
      GLDS(ksb + (size_t)(kbase + c * 64) * 64 + id * 512 + lane * 8, &lk[buf][id * 512]);
      GLDS(vcb + (size_t)(kc0 + c) * 4096 + id * 512 + lane * 8, &lv[buf][id * 512]);
    }
  };

  // persistent Q B-fragments (16x16x32): B[k=d=quad*8+j][col=q=n]
  f16x8 qf[2][2];
#pragma unroll
  for (int g = 0; g < 2; ++g)
#pragma unroll
    for (int hh = 0; hh < 2; ++hh)
      qf[g][hh] = *(const f16x8*)(qs + (size_t)(row0 + g * 16 + n) * DDIM + hh * 32 + quad * 8);

  // swizzle read offsets (per-lane constants)
  const int kswz = (quad ^ (n & 7)) << 3;          // klo block; khi = kswz ^ 32
  int vswz[4];
#pragma unroll
  for (int st = 0; st < 4; ++st) vswz[st] = ((((st << 2) | quad) ^ n) << 2);

  f32x4 acc[2][4];
  float m[2] = {-1e30f, -1e30f}, ll[2] = {0.f, 0.f};
#pragma unroll
  for (int g = 0; g < 2; ++g)
#pragma unroll
    for (int t = 0; t < 4; ++t) acc[g][t] = (f32x4){0.f, 0.f, 0.f, 0.f};

  issue(0, 0);
  for (int c = 0; c < NC; ++c) {
    const int b = c & 1;
    __syncthreads();                      // drains chunk c's DMA; guards buffers
    if (c + 1 < NC) issue(c + 1, b ^ 1);  // in flight across entire compute phase

    // S' = K·Q^T
    f32x4 s[2][4];
#pragma unroll
    for (int st = 0; st < 4; ++st) {
      const f16* lkr = &lk[b][(st * 16 + n) * 64];
      const f16x8 klo = *(const f16x8*)(lkr + kswz);
      const f16x8 khi = *(const f16x8*)(lkr + (kswz ^ 32));
#pragma unroll
      for (int g = 0; g < 2; ++g) {
        f32x4 z = (f32x4){0.f, 0.f, 0.f, 0.f};
        z = MFMA32(klo, qf[g][0], z);
        s[g][st] = MFMA32(khi, qf[g][1], z);
      }
    }

    // per-lane online softmax; P packed directly as 16x16x16 B-fragments
    f16x4 pq[2][4];
#pragma unroll
    for (int g = 0; g < 2; ++g) {
      f32x4 mx;
#pragma unroll
      for (int r = 0; r < 4; ++r)
        mx[r] = fmaxf(fmaxf(s[g][0][r], s[g][1][r]), fmaxf(s[g][2][r], s[g][3][r]));
      float mloc = fmaxf(fmaxf(mx[0], mx[1]), fmaxf(mx[2], mx[3]));
      mloc = fmaxf(mloc, __shfl_xor(mloc, 16));
      mloc = fmaxf(mloc, __shfl_xor(mloc, 32));
      const float mnew = fmaxf(m[g], mloc);
      const float alpha = __builtin_amdgcn_exp2f(m[g] - mnew);
      m[g] = mnew;
      float psum = 0.f;
#pragma unroll
      for (int st = 0; st < 4; ++st) {
        f32x4 p;
#pragma unroll
        for (int r = 0; r < 4; ++r) p[r] = __builtin_amdgcn_exp2f(s[g][st][r] - mnew);
        psum += (p[0] + p[1]) + (p[2] + p[3]);
        pq[g][st] = cvt4(p[0], p[1], p[2], p[3]);
      }
      ll[g] = ll[g] * alpha + psum;
#pragma unroll
      for (int t = 0; t < 4; ++t) acc[g][t] *= alpha;
    }

    // O^T += V^T·P^T : A = V^T frag [m=d][k=key quad*4+j] (swizzled LDS read)
#pragma unroll
    for (int dt = 0; dt < 4; ++dt) {
      const f16* lvr = &lv[b][(dt * 16 + n) * 64];
#pragma unroll
      for (int st = 0; st < 4; ++st) {
        const f16x4 va = *(const f16x4*)(lvr + vswz[st]);
        acc[0][dt] = MFMA16(va, pq[0][st], acc[0][dt]);
        acc[1][dt] = MFMA16(va, pq[1][st], acc[1][dt]);
      }
    }
  }

  float lred[2];
#pragma unroll
  for (int g = 0; g < 2; ++g) {
    float l = ll[g];
    l += __shfl_xor(l, 16);
    l += __shfl_xor(l, 32);
    lred[g] = l;
  }

  if (NSPLIT == 1) {
#pragma unroll
    for (int g = 0; g < 2; ++g) {
      const float inv = 1.0f / lred[g];
      const int q = row0 + g * 16 + n;
#pragma unroll
      for (int t = 0; t < 4; ++t) {
        f32x4 o = acc[g][t];
#pragma unroll
        for (int r = 0; r < 4; ++r) o[r] *= inv;
        *(f32x4*)(outp + (size_t)q * DDIM + t * 16 + quad * 4) = o;
      }
    }
  } else {
#pragma unroll
    for (int g = 0; g < 2; ++g) {
      const int q = row0 + g * 16 + n;
#pragma unroll
      for (int t = 0; t < 4; ++t)
        *(f16x4*)(pacc + ((size_t)split * NROW + q) * DDIM + t * 16 + quad * 4) =
            cvt4(acc[g][t][0], acc[g][t][1], acc[g][t][2], acc[g][t][3]);
      if (quad == 0) {
        pm[split * NROW + q] = m[g];
        pl[split * NROW + q] = lred[g];
      }
    }
  }
}

// ---------------- attn split-K combine (f16 partials) ----------------
template <int NSPLIT>
__global__ __launch_bounds__(256) void combine_kernel(const f16* __restrict__ pacc,
                                                      const float* __restrict__ pm,
                                                      const float* __restrict__ pl,
                                                      float* __restrict__ out) {
  const int idx = blockIdx.x * 256 + threadIdx.x;  // NROW*16 units
  const int row = idx >> 4;
  const int c = (idx & 15) * 4;
  float mm = pm[row];
#pragma unroll
  for (int s = 1; s < NSPLIT; ++s) mm = fmaxf(mm, pm[s * NROW + row]);
  float L = 0.f;
  f32x4 o = (f32x4){0.f, 0.f, 0.f, 0.f};
#pragma unroll
  for (int s = 0; s < NSPLIT; ++s) {
    const float e = __builtin_amdgcn_exp2f(pm[s * NROW + row] - mm);
    L += pl[s * NROW + row] * e;
    const f16x4 a = *(const f16x4*)(pacc + ((size_t)s * NROW + row) * DDIM + c);
#pragma unroll
    for (int j = 0; j < 4; ++j) o[j] += (float)a[j] * e;
  }
  const float inv = 1.0f / L;
#pragma unroll
  for (int j = 0; j < 4; ++j) o[j] *= inv;
  *(f32x4*)(out + (size_t)row * DDIM + c) = o;
}

extern "C" void kernel_launch(void* const* d_in, const int* in_sizes, int n_in,
                              void* d_out, int out_size, void* d_ws, size_t ws_size,
                              hipStream_t stream) {
  const float* x  = (const float*)d_in[0];
  const float* Wq = (const float*)d_in[1];
  const float* bq = (const float*)d_in[2];
  const float* Wk = (const float*)d_in[3];
  const float* bk = (const float*)d_in[4];
  const float* Wv = (const float*)d_in[5];
  const float* bv = (const float*)d_in[6];
  float* out = (float*)d_out;

  f16* wf2 = (f16*)d_ws;                      // 3*64*1024 f16, chunk-slot layout
  f16* qs = wf2 + 3 * 65536;
  f16* ks = qs + (size_t)SEG;                 // block-swizzled
  f16* vc = ks + (size_t)SEG;                 // chunk-major tiles, swizzled
  f16* pacc = vc + (size_t)SEG;               // [NSPL][NROW][64] f16 attn partials
  float* pm = (float*)(pacc + (size_t)NSPL * SEG);
  float* pl = pm + (size_t)NSPL * NROW;
  const size_t need = (size_t)((char*)(pl + (size_t)NSPL * NROW) - (char*)d_ws);

  prep_w_kernel<<<dim3(96), dim3(256), 0, stream>>>(Wq, Wk, Wv, wf2);
  proj_kernel<<<dim3(512), dim3(256), 0, stream>>>(x, wf2, bq, bk, bv, qs, ks, vc);

  if (ws_size >= need) {
    attn_kernel<NSPL><<<dim3(128 * NSPL), dim3(256), 0, stream>>>(qs, ks, vc, nullptr, pacc, pm, pl);
    combine_kernel<NSPL><<<dim3(NROW * 16 / 256), dim3(256), 0, stream>>>(pacc, pm, pl, out);
  } else {
    attn_kernel<1><<<dim3(128), dim3(256), 0, stream>>>(qs, ks, vc, out, nullptr, nullptr, nullptr);
  }
}

// Round 4
// 165.371 us; speedup vs baseline: 1.1304x; 1.0384x over previous
//
#include <hip/hip_runtime.h>

#define BATCH 4
#define SEQ   4096
#define CDIM  1024
#define DDIM  64
#define NROW  (BATCH * SEQ)   // 16384
#define NSPL  8               // attn key-split
#define SEG   (NROW * DDIM)   // 1M elements per q/k/v buffer

typedef _Float16 f16;
typedef _Float16 f16x8 __attribute__((ext_vector_type(8)));
typedef _Float16 f16x4 __attribute__((ext_vector_type(4)));
typedef __fp16   h16x2 __attribute__((ext_vector_type(2)));  // cvt_pkrtz return type
typedef float    f32x4 __attribute__((ext_vector_type(4)));

#define MFMA32(a, b, c) __builtin_amdgcn_mfma_f32_16x16x32_f16((a), (b), (c), 0, 0, 0)
#define MFMA16(a, b, c) __builtin_amdgcn_mfma_f32_16x16x16f16((a), (b), (c), 0, 0, 0)

// async global->LDS DMA, 16 B per lane; LDS dest = wave-uniform base + lane*16
#define GLDS(g, l)                                                            \
  __builtin_amdgcn_global_load_lds((const __attribute__((address_space(1))) void*)(g), \
                                   (__attribute__((address_space(3))) void*)(l), 16, 0, 0)

// scores = (q·k)*8 (the /scale bug); softmax in exp2 domain => fold 8*log2(e) into q
#define QSCALE 11.5415603f

__device__ inline f16x8 cvt8(f32x4 a, f32x4 b) {
  h16x2 p0 = __builtin_amdgcn_cvt_pkrtz(a[0], a[1]);
  h16x2 p1 = __builtin_amdgcn_cvt_pkrtz(a[2], a[3]);
  h16x2 p2 = __builtin_amdgcn_cvt_pkrtz(b[0], b[1]);
  h16x2 p3 = __builtin_amdgcn_cvt_pkrtz(b[2], b[3]);
  f16x8 r;
  r[0] = p0[0]; r[1] = p0[1]; r[2] = p1[0]; r[3] = p1[1];
  r[4] = p2[0]; r[5] = p2[1]; r[6] = p3[0]; r[7] = p3[1];
  return r;
}

__device__ inline f16x4 cvt4(float a, float b, float c, float d) {
  h16x2 lo = __builtin_amdgcn_cvt_pkrtz(a, b);
  h16x2 hi = __builtin_amdgcn_cvt_pkrtz(c, d);
  f16x4 r;
  r[0] = lo[0]; r[1] = lo[1]; r[2] = hi[0]; r[3] = hi[1];
  return r;
}

// ---------------- W prep: fp32 -> f16, mt-major fragment order ---------------
// wf2 slot s = mt*32 + ck (mt = mat*4+tile 0..11, ck = 32-ch chunk 0..31),
// 512 f16 per slot. Lane l of slot s holds B-frag bytes l*16:
// W[tile*16+n][ck*32+quad*8+j]. mt-major => per-mt W stream is contiguous 32KB.
__global__ __launch_bounds__(256) void prep_w_kernel(const float* __restrict__ Wq,
                                                     const float* __restrict__ Wk,
                                                     const float* __restrict__ Wv,
                                                     f16* __restrict__ wf2) {
  const int t = blockIdx.x * 256 + threadIdx.x;  // 96 blocks -> 24576 threads
  const int lane = t & 63;
  const int s = t >> 6;                // 0..383
  const int mt = s >> 5, ck = s & 31;
  const int mat = mt >> 2, tile = mt & 3;
  const int n = lane & 15, quad = lane >> 4;
  const float* W = (mat == 0) ? Wq : (mat == 1) ? Wk : Wv;
  const float* src = W + (size_t)(tile * 16 + n) * CDIM + ck * 32 + quad * 8;
  const f32x4 a = *(const f32x4*)src;
  const f32x4 b = *(const f32x4*)(src + 4);
  *(f16x8*)(wf2 + (size_t)t * 8) = cvt8(a, b);
}

// ---------------- fused QKV projection: x-stationary register GEMM -----------
// Round-3 post-mortem: VGPR=56 proves the compiler collapsed the rotating
// double-buffer and serialized loads (0.9 TB/s, all idle). Fix: make the
// parallelism structural. Phase 1: wave streams its 16 x-rows into 128 VGPRs
// of f16 A-frags -- 64 independent dwordx4 loads, all results live => cannot
// be serialized, full HBM rate. Phase 2: only the L2-resident W stream
// remains: per 3-mt pass, 96 independent coalesced 1KB loads feed 3
// independent MFMA chains; epilogue per pass keeps acc live-range short.
// Wave = 16 rows x 6 mt; block = 4 waves = 32 rows x 12 mt; 512 blocks;
// launch_bounds(256,2) caps VGPR at 256 (expect ~200-230, 8 waves/CU).
__global__ __launch_bounds__(256, 2) void proj_kernel(const float* __restrict__ x,
                                                      const f16* __restrict__ wf2,
                                                      const float* __restrict__ bq,
                                                      const float* __restrict__ bk,
                                                      const float* __restrict__ bv,
                                                      f16* __restrict__ qs,
                                                      f16* __restrict__ ks,
                                                      f16* __restrict__ vc) {
  const int tid = threadIdx.x, lane = tid & 63, w = tid >> 6;  // w 0..3
  const int n = lane & 15, quad = lane >> 4;
  const int row16 = blockIdx.x * 32 + (w & 1) * 16;  // wave's 16-row stripe
  const int mtb = (w >> 1) * 6;                      // wave's 6-mt half

  // ---- phase 1: x -> 128 f16 VGPRs (A-frags for all 32 K-chunks) ----
  const float* xp = x + (size_t)(row16 + n) * CDIM + quad * 8;
  f16x8 xf[32];
#pragma unroll
  for (int ck = 0; ck < 32; ++ck) {
    const f32x4 a = *(const f32x4*)(xp + ck * 32);
    const f32x4 c = *(const f32x4*)(xp + ck * 32 + 4);
    xf[ck] = cvt8(a, c);
  }

  // ---- phase 2: two passes of 3 mt; W streamed from L2-resident wf2 ----
  const f16* wl = wf2 + (size_t)lane * 8;
#pragma unroll
  for (int p = 0; p < 2; ++p) {
    const int m0 = mtb + p * 3;
    const f16* wb = wl + (size_t)m0 * 16384;  // mt stride = 32 slots * 512 f16
    f32x4 acc[3];
#pragma unroll
    for (int i = 0; i < 3; ++i) acc[i] = (f32x4){0.f, 0.f, 0.f, 0.f};
#pragma unroll
    for (int ck = 0; ck < 32; ++ck) {
      const f16x8 w0 = *(const f16x8*)(wb + ck * 512);
      const f16x8 w1 = *(const f16x8*)(wb + 16384 + ck * 512);
      const f16x8 w2 = *(const f16x8*)(wb + 32768 + ck * 512);
      acc[0] = MFMA32(xf[ck], w0, acc[0]);
      acc[1] = MFMA32(xf[ck], w1, acc[1]);
      acc[2] = MFMA32(xf[ck], w2, acc[2]);
    }

    // epilogue for this pass: bias + final layouts (q*QSCALE, k swz, v tiles)
    const int r0 = row16 + quad * 4;
#pragma unroll
    for (int i2 = 0; i2 < 3; ++i2) {
      const int mt = m0 + i2;
      const int mat = mt >> 2, tile = mt & 3;
      const int d = tile * 16 + n;  // d&15 == n
      const f32x4 aa = acc[i2];
      if (mat == 0) {
        const float bi = bq[d];
#pragma unroll
        for (int r = 0; r < 4; ++r)
          qs[(size_t)(r0 + r) * DDIM + d] = (f16)((aa[r] + bi) * QSCALE);
      } else if (mat == 1) {
        const float bi = bk[d];
#pragma unroll
        for (int r = 0; r < 4; ++r) {
          const int tt = r0 + r;
          const int col = ((((d >> 3) ^ (tt & 7)) << 3) | (d & 7));
          ks[(size_t)tt * DDIM + col] = (f16)(aa[r] + bi);
        }
      } else {
        const float bi = bv[d];
        const int bb = r0 >> 12;
        const int tl = r0 & (SEQ - 1);
        const int ck2 = tl >> 6;
        const int bsw = (((tl & 63) >> 2) ^ n) << 2;
        *(f16x4*)(vc + ((size_t)(bb * 64 + ck2) * 64 + d) * 64 + bsw) =
            cvt4(aa[0] + bi, aa[1] + bi, aa[2] + bi, aa[3] + bi);
      }
    }
  }
}

// ---------------- flash attention: DMA-staged K/V, dbuf, 1 barrier/chunk ------
// S' = K·Q^T (C-layout row=key, col=q), per-lane softmax, P stays in registers
// as 16x16x16 B-fragments. K/V tiles DMA'd contiguously (8 KB each) into
// unpadded LDS; swizzled global layouts make fragment reads phase-optimal.
template <int NSPLIT>
__global__ __launch_bounds__(256, 4) void attn_kernel(const f16* __restrict__ qs,
                                                      const f16* __restrict__ ks,
                                                      const f16* __restrict__ vc,
                                                      float* __restrict__ outp,
                                                      f16* __restrict__ pacc,
                                                      float* __restrict__ pm,
                                                      float* __restrict__ pl) {
  __shared__ __attribute__((aligned(16))) f16 lk[2][4096];  // [buf][key][64 d swz]
  __shared__ __attribute__((aligned(16))) f16 lv[2][4096];  // [buf][d][64 key swz]
  const int tid = threadIdx.x, lane = tid & 63, w = tid >> 6;
  const int n = lane & 15, quad = lane >> 4;
  const int split = blockIdx.x % NSPLIT;
  const int rowblk = blockIdx.x / NSPLIT;
  const int row0 = rowblk * 128 + w * 32;
  const int bb = row0 >> 12;
  const int kbase = split * (SEQ / NSPLIT);
  const int kc0 = kbase >> 6;
  const int NC = SEQ / NSPLIT / 64;

  const f16* ksb = ks + (size_t)bb * SEQ * DDIM;
  const f16* vcb = vc + (size_t)bb * 64 * 4096;

  auto issue = [&](int c, int buf) {
#pragma unroll
    for (int i = 0; i < 2; ++i) {
      const int id = 2 * w + i;
      GLDS(ksb + (size_t)(kbase + c * 64) * 64 + id * 512 + lane * 8, &lk[buf][id * 512]);
      GLDS(vcb + (size_t)(kc0 + c) * 4096 + id * 512 + lane * 8, &lv[buf][id * 512]);
    }
  };

  // persistent Q B-fragments (16x16x32): B[k=d=quad*8+j][col=q=n]
  f16x8 qf[2][2];
#pragma unroll
  for (int g = 0; g < 2; ++g)
#pragma unroll
    for (int hh = 0; hh < 2; ++hh)
      qf[g][hh] = *(const f16x8*)(qs + (size_t)(row0 + g * 16 + n) * DDIM + hh * 32 + quad * 8);

  // swizzle read offsets (per-lane constants)
  const int kswz = (quad ^ (n & 7)) << 3;          // klo block; khi = kswz ^ 32
  int vswz[4];
#pragma unroll
  for (int st = 0; st < 4; ++st) vswz[st] = ((((st << 2) | quad) ^ n) << 2);

  f32x4 acc[2][4];
  float m[2] = {-1e30f, -1e30f}, ll[2] = {0.f, 0.f};
#pragma unroll
  for (int g = 0; g < 2; ++g)
#pragma unroll
    for (int t = 0; t < 4; ++t) acc[g][t] = (f32x4){0.f, 0.f, 0.f, 0.f};

  issue(0, 0);
  for (int c = 0; c < NC; ++c) {
    const int b = c & 1;
    __syncthreads();                      // drains chunk c's DMA; guards buffers
    if (c + 1 < NC) issue(c + 1, b ^ 1);  // in flight across entire compute phase

    // S' = K·Q^T
    f32x4 s[2][4];
#pragma unroll
    for (int st = 0; st < 4; ++st) {
      const f16* lkr = &lk[b][(st * 16 + n) * 64];
      const f16x8 klo = *(const f16x8*)(lkr + kswz);
      const f16x8 khi = *(const f16x8*)(lkr + (kswz ^ 32));
#pragma unroll
      for (int g = 0; g < 2; ++g) {
        f32x4 z = (f32x4){0.f, 0.f, 0.f, 0.f};
        z = MFMA32(klo, qf[g][0], z);
        s[g][st] = MFMA32(khi, qf[g][1], z);
      }
    }

    // per-lane online softmax; P packed directly as 16x16x16 B-fragments
    f16x4 pq[2][4];
#pragma unroll
    for (int g = 0; g < 2; ++g) {
      f32x4 mx;
#pragma unroll
      for (int r = 0; r < 4; ++r)
        mx[r] = fmaxf(fmaxf(s[g][0][r], s[g][1][r]), fmaxf(s[g][2][r], s[g][3][r]));
      float mloc = fmaxf(fmaxf(mx[0], mx[1]), fmaxf(mx[2], mx[3]));
      mloc = fmaxf(mloc, __shfl_xor(mloc, 16));
      mloc = fmaxf(mloc, __shfl_xor(mloc, 32));
      const float mnew = fmaxf(m[g], mloc);
      const float alpha = __builtin_amdgcn_exp2f(m[g] - mnew);
      m[g] = mnew;
      float psum = 0.f;
#pragma unroll
      for (int st = 0; st < 4; ++st) {
        f32x4 p;
#pragma unroll
        for (int r = 0; r < 4; ++r) p[r] = __builtin_amdgcn_exp2f(s[g][st][r] - mnew);
        psum += (p[0] + p[1]) + (p[2] + p[3]);
        pq[g][st] = cvt4(p[0], p[1], p[2], p[3]);
      }
      ll[g] = ll[g] * alpha + psum;
#pragma unroll
      for (int t = 0; t < 4; ++t) acc[g][t] *= alpha;
    }

    // O^T += V^T·P^T : A = V^T frag [m=d][k=key quad*4+j] (swizzled LDS read)
#pragma unroll
    for (int dt = 0; dt < 4; ++dt) {
      const f16* lvr = &lv[b][(dt * 16 + n) * 64];
#pragma unroll
      for (int st = 0; st < 4; ++st) {
        const f16x4 va = *(const f16x4*)(lvr + vswz[st]);
        acc[0][dt] = MFMA16(va, pq[0][st], acc[0][dt]);
        acc[1][dt] = MFMA16(va, pq[1][st], acc[1][dt]);
      }
    }
  }

  float lred[2];
#pragma unroll
  for (int g = 0; g < 2; ++g) {
    float l = ll[g];
    l += __shfl_xor(l, 16);
    l += __shfl_xor(l, 32);
    lred[g] = l;
  }

  if (NSPLIT == 1) {
#pragma unroll
    for (int g = 0; g < 2; ++g) {
      const float inv = 1.0f / lred[g];
      const int q = row0 + g * 16 + n;
#pragma unroll
      for (int t = 0; t < 4; ++t) {
        f32x4 o = acc[g][t];
#pragma unroll
        for (int r = 0; r < 4; ++r) o[r] *= inv;
        *(f32x4*)(outp + (size_t)q * DDIM + t * 16 + quad * 4) = o;
      }
    }
  } else {
#pragma unroll
    for (int g = 0; g < 2; ++g) {
      const int q = row0 + g * 16 + n;
#pragma unroll
      for (int t = 0; t < 4; ++t)
        *(f16x4*)(pacc + ((size_t)split * NROW + q) * DDIM + t * 16 + quad * 4) =
            cvt4(acc[g][t][0], acc[g][t][1], acc[g][t][2], acc[g][t][3]);
      if (quad == 0) {
        pm[split * NROW + q] = m[g];
        pl[split * NROW + q] = lred[g];
      }
    }
  }
}

// ---------------- attn split-K combine (f16 partials) ----------------
template <int NSPLIT>
__global__ __launch_bounds__(256) void combine_kernel(const f16* __restrict__ pacc,
                                                      const float* __restrict__ pm,
                                                      const float* __restrict__ pl,
                                                      float* __restrict__ out) {
  const int idx = blockIdx.x * 256 + threadIdx.x;  // NROW*16 units
  const int row = idx >> 4;
  const int c = (idx & 15) * 4;
  float mm = pm[row];
#pragma unroll
  for (int s = 1; s < NSPLIT; ++s) mm = fmaxf(mm, pm[s * NROW + row]);
  float L = 0.f;
  f32x4 o = (f32x4){0.f, 0.f, 0.f, 0.f};
#pragma unroll
  for (int s = 0; s < NSPLIT; ++s) {
    const float e = __builtin_amdgcn_exp2f(pm[s * NROW + row] - mm);
    L += pl[s * NROW + row] * e;
    const f16x4 a = *(const f16x4*)(pacc + ((size_t)s * NROW + row) * DDIM + c);
#pragma unroll
    for (int j = 0; j < 4; ++j) o[j] += (float)a[j] * e;
  }
  const float inv = 1.0f / L;
#pragma unroll
  for (int j = 0; j < 4; ++j) o[j] *= inv;
  *(f32x4*)(out + (size_t)row * DDIM + c) = o;
}

extern "C" void kernel_launch(void* const* d_in, const int* in_sizes, int n_in,
                              void* d_out, int out_size, void* d_ws, size_t ws_size,
                              hipStream_t stream) {
  const float* x  = (const float*)d_in[0];
  const float* Wq = (const float*)d_in[1];
  const float* bq = (const float*)d_in[2];
  const float* Wk = (const float*)d_in[3];
  const float* bk = (const float*)d_in[4];
  const float* Wv = (const float*)d_in[5];
  const float* bv = (const float*)d_in[6];
  float* out = (float*)d_out;

  f16* wf2 = (f16*)d_ws;                      // 3*64*1024 f16, mt-major slots
  f16* qs = wf2 + 3 * 65536;
  f16* ks = qs + (size_t)SEG;                 // block-swizzled
  f16* vc = ks + (size_t)SEG;                 // chunk-major tiles, swizzled
  f16* pacc = vc + (size_t)SEG;               // [NSPL][NROW][64] f16 attn partials
  float* pm = (float*)(pacc + (size_t)NSPL * SEG);
  float* pl = pm + (size_t)NSPL * NROW;
  const size_t need = (size_t)((char*)(pl + (size_t)NSPL * NROW) - (char*)d_ws);

  prep_w_kernel<<<dim3(96), dim3(256), 0, stream>>>(Wq, Wk, Wv, wf2);
  proj_kernel<<<dim3(512), dim3(256), 0, stream>>>(x, wf2, bq, bk, bv, qs, ks, vc);

  if (ws_size >= need) {
    attn_kernel<NSPL><<<dim3(128 * NSPL), dim3(256), 0, stream>>>(qs, ks, vc, nullptr, pacc, pm, pl);
    combine_kernel<NSPL><<<dim3(NROW * 16 / 256), dim3(256), 0, stream>>>(pacc, pm, pl, out);
  } else {
    attn_kernel<1><<<dim3(128), dim3(256), 0, stream>>>(qs, ks, vc, out, nullptr, nullptr, nullptr);
  }
}

// Round 5
// 154.512 us; speedup vs baseline: 1.2098x; 1.0703x over previous
//
#include <hip/hip_runtime.h>

#define BATCH 4
#define SEQ   4096
#define CDIM  1024
#define DDIM  64
#define NROW  (BATCH * SEQ)   // 16384
#define NSPL  8               // attn key-split
#define SEG   (NROW * DDIM)   // 1M elements per q/k/v buffer

typedef _Float16 f16;
typedef _Float16 f16x8 __attribute__((ext_vector_type(8)));
typedef _Float16 f16x4 __attribute__((ext_vector_type(4)));
typedef __fp16   h16x2 __attribute__((ext_vector_type(2)));  // cvt_pkrtz return type
typedef float    f32x4 __attribute__((ext_vector_type(4)));

#define MFMA32(a, b, c) __builtin_amdgcn_mfma_f32_16x16x32_f16((a), (b), (c), 0, 0, 0)
#define MFMA16(a, b, c) __builtin_amdgcn_mfma_f32_16x16x16f16((a), (b), (c), 0, 0, 0)

// async global->LDS DMA, 16 B per lane; LDS dest = wave-uniform base + lane*16
#define GLDS(g, l)                                                            \
  __builtin_amdgcn_global_load_lds((const __attribute__((address_space(1))) void*)(g), \
                                   (__attribute__((address_space(3))) void*)(l), 16, 0, 0)

// scores = (q·k)*8 (the /scale bug); softmax in exp2 domain => fold 8*log2(e) into q
#define QSCALE 11.5415603f

__device__ inline f16x8 cvt8(f32x4 a, f32x4 b) {
  h16x2 p0 = __builtin_amdgcn_cvt_pkrtz(a[0], a[1]);
  h16x2 p1 = __builtin_amdgcn_cvt_pkrtz(a[2], a[3]);
  h16x2 p2 = __builtin_amdgcn_cvt_pkrtz(b[0], b[1]);
  h16x2 p3 = __builtin_amdgcn_cvt_pkrtz(b[2], b[3]);
  f16x8 r;
  r[0] = p0[0]; r[1] = p0[1]; r[2] = p1[0]; r[3] = p1[1];
  r[4] = p2[0]; r[5] = p2[1]; r[6] = p3[0]; r[7] = p3[1];
  return r;
}

__device__ inline f16x4 cvt4(float a, float b, float c, float d) {
  h16x2 lo = __builtin_amdgcn_cvt_pkrtz(a, b);
  h16x2 hi = __builtin_amdgcn_cvt_pkrtz(c, d);
  f16x4 r;
  r[0] = lo[0]; r[1] = lo[1]; r[2] = hi[0]; r[3] = hi[1];
  return r;
}

// ---------------- W prep: fp32 -> f16, mt-major fragment order ---------------
// wf2 slot s = mt*32 + ck (mt = mat*4+tile 0..11, ck = 32-ch chunk 0..31),
// 512 f16 per slot. Lane l of slot s holds B-frag bytes l*16:
// W[tile*16+n][ck*32+quad*8+j]. mt-major => per-mt W stream is contiguous 32KB.
__global__ __launch_bounds__(256) void prep_w_kernel(const float* __restrict__ Wq,
                                                     const float* __restrict__ Wk,
                                                     const float* __restrict__ Wv,
                                                     f16* __restrict__ wf2) {
  const int t = blockIdx.x * 256 + threadIdx.x;  // 96 blocks -> 24576 threads
  const int lane = t & 63;
  const int s = t >> 6;                // 0..383
  const int mt = s >> 5, ck = s & 31;
  const int mat = mt >> 2, tile = mt & 3;
  const int n = lane & 15, quad = lane >> 4;
  const float* W = (mat == 0) ? Wq : (mat == 1) ? Wk : Wv;
  const float* src = W + (size_t)(tile * 16 + n) * CDIM + ck * 32 + quad * 8;
  const f32x4 a = *(const f32x4*)src;
  const f32x4 b = *(const f32x4*)(src + 4);
  *(f16x8*)(wf2 + (size_t)t * 8) = cvt8(a, b);
}

// ---------------- fused QKV projection: DMA-staged x, register W -------------
// Round-4 post-mortem: register-staged x streaming is VGPR-starved (~24
// outstanding 16B loads x 8 waves/CU = 3.4 B/cyc << 10.2 needed for HBM peak)
// -> 39 us. Fix: stage x via global_load_lds (in-flight bytes cost ZERO VGPR),
// with round-2's failure modes removed: 16-row blocks, 16 KB LDS, lean body
// -> 4 blocks/CU co-resident (grid 1024 = 4/CU exactly); chunk = 128 ch (8 KB
// staged / 8 GLDS); per-CU in-flight = 32 KB -> 36 B/cyc HBM feasible. Per
// chunk per wave: 12 MFMA + 8 ds_read_b128 + 12 L2-resident W reg-loads; the
// other 3 blocks cover each block's barrier drain (m114). x LDS XOR-swizzled
// via pre-swizzled global source (linear GLDS dest): pos p = c ^ row within
// each 512B row -> A-frag reads 2-way max (free). Wave w owns mt 3w..3w+2.
__global__ __launch_bounds__(256, 4) void proj_kernel(const float* __restrict__ x,
                                                      const f16* __restrict__ wf2,
                                                      const float* __restrict__ bq,
                                                      const float* __restrict__ bk,
                                                      const float* __restrict__ bv,
                                                      f16* __restrict__ qs,
                                                      f16* __restrict__ ks,
                                                      f16* __restrict__ vc) {
  __shared__ __attribute__((aligned(16))) char lx[2][8192];  // [buf][16 rows x 512B swz]
  const int tid = threadIdx.x, lane = tid & 63, w = tid >> 6;  // w 0..3
  const int n = lane & 15, quad = lane >> 4;
  const int rowbase = blockIdx.x * 16;
  const int mtb = 3 * w;

  // DMA sources: wave w instr j covers rows 2*(2w+j)..+1, LDS pos p = lane&31.
  // Source pre-swizzle: 16B chunk c = p ^ r  (involution; read undoes with ^n).
  const float* xsrc[2];
#pragma unroll
  for (int j = 0; j < 2; ++j) {
    const int id = 2 * w + j;
    const int r = id * 2 + (lane >> 5);
    const int c = (lane & 31) ^ r;
    xsrc[j] = x + (size_t)(rowbase + r) * CDIM + c * 4;
  }

  auto issue = [&](int ck, int b) {
    char* base = &lx[b][0];
#pragma unroll
    for (int j = 0; j < 2; ++j)
      GLDS(xsrc[j] + ck * 128, base + (2 * w + j) * 1024);
  };

  const f16* wl = wf2 + (size_t)mtb * 16384 + lane * 8;  // + (ck*4+kk)*512

  f32x4 acc[3];
#pragma unroll
  for (int i = 0; i < 3; ++i) acc[i] = (f32x4){0.f, 0.f, 0.f, 0.f};

  issue(0, 0);
  for (int ck = 0; ck < 8; ++ck) {
    const int b = ck & 1;
    __syncthreads();                       // drains chunk ck's DMA
    if (ck + 1 < 8) issue(ck + 1, b ^ 1);  // in flight across compute
    const char* xb = &lx[b][0] + n * 512;
#pragma unroll
    for (int kk = 0; kk < 4; ++kk) {
      const int c1 = kk * 8 + quad * 2;
      const f32x4 xa = *(const f32x4*)(xb + ((c1 ^ n) << 4));
      const f32x4 xc = *(const f32x4*)(xb + (((c1 + 1) ^ n) << 4));
      const f16x8 af = cvt8(xa, xc);
      const f16* wq = wl + (size_t)(ck * 4 + kk) * 512;
      const f16x8 w0 = *(const f16x8*)(wq);
      const f16x8 w1 = *(const f16x8*)(wq + 16384);
      const f16x8 w2 = *(const f16x8*)(wq + 32768);
      acc[0] = MFMA32(af, w0, acc[0]);
      acc[1] = MFMA32(af, w1, acc[1]);
      acc[2] = MFMA32(af, w2, acc[2]);
    }
  }

  // epilogue: bias + final layouts (q*QSCALE, k swizzled, v tiles)
  const int r0 = rowbase + quad * 4;
#pragma unroll
  for (int i2 = 0; i2 < 3; ++i2) {
    const int mt = mtb + i2;
    const int mat = mt >> 2, tile = mt & 3;
    const int d = tile * 16 + n;  // d&15 == n
    const f32x4 aa = acc[i2];
    if (mat == 0) {
      const float bi = bq[d];
#pragma unroll
      for (int r = 0; r < 4; ++r)
        qs[(size_t)(r0 + r) * DDIM + d] = (f16)((aa[r] + bi) * QSCALE);
    } else if (mat == 1) {
      const float bi = bk[d];
#pragma unroll
      for (int r = 0; r < 4; ++r) {
        const int tt = r0 + r;
        const int col = ((((d >> 3) ^ (tt & 7)) << 3) | (d & 7));
        ks[(size_t)tt * DDIM + col] = (f16)(aa[r] + bi);
      }
    } else {
      const float bi = bv[d];
      const int bb = r0 >> 12;
      const int tl = r0 & (SEQ - 1);
      const int ck2 = tl >> 6;
      const int bsw = (((tl & 63) >> 2) ^ n) << 2;
      *(f16x4*)(vc + ((size_t)(bb * 64 + ck2) * 64 + d) * 64 + bsw) =
          cvt4(aa[0] + bi, aa[1] + bi, aa[2] + bi, aa[3] + bi);
    }
  }
}

// ---------------- flash attention: DMA-staged K/V, dbuf, 1 barrier/chunk ------
// S' = K·Q^T (C-layout row=key, col=q), per-lane softmax, P stays in registers
// as 16x16x16 B-fragments. K/V tiles DMA'd contiguously (8 KB each) into
// unpadded LDS; swizzled global layouts make fragment reads phase-optimal.
template <int NSPLIT>
__global__ __launch_bounds__(256, 4) void attn_kernel(const f16* __restrict__ qs,
                                                      const f16* __restrict__ ks,
                                                      const f16* __restrict__ vc,
                                                      float* __restrict__ outp,
                                                      f16* __restrict__ pacc,
                                                      float* __restrict__ pm,
                                                      float* __restrict__ pl) {
  __shared__ __attribute__((aligned(16))) f16 lk[2][4096];  // [buf][key][64 d swz]
  __shared__ __attribute__((aligned(16))) f16 lv[2][4096];  // [buf][d][64 key swz]
  const int tid = threadIdx.x, lane = tid & 63, w = tid >> 6;
  const int n = lane & 15, quad = lane >> 4;
  const int split = blockIdx.x % NSPLIT;
  const int rowblk = blockIdx.x / NSPLIT;
  const int row0 = rowblk * 128 + w * 32;
  const int bb = row0 >> 12;
  const int kbase = split * (SEQ / NSPLIT);
  const int kc0 = kbase >> 6;
  const int NC = SEQ / NSPLIT / 64;

  const f16* ksb = ks + (size_t)bb * SEQ * DDIM;
  const f16* vcb = vc + (size_t)bb * 64 * 4096;

  auto issue = [&](int c, int buf) {
#pragma unroll
    for (int i = 0; i < 2; ++i) {
      const int id = 2 * w + i;
      GLDS(ksb + (size_t)(kbase + c * 64) * 64 + id * 512 + lane * 8, &lk[buf][id * 512]);
      GLDS(vcb + (size_t)(kc0 + c) * 4096 + id * 512 + lane * 8, &lv[buf][id * 512]);
    }
  };

  // persistent Q B-fragments (16x16x32): B[k=d=quad*8+j][col=q=n]
  f16x8 qf[2][2];
#pragma unroll
  for (int g = 0; g < 2; ++g)
#pragma unroll
    for (int hh = 0; hh < 2; ++hh)
      qf[g][hh] = *(const f16x8*)(qs + (size_t)(row0 + g * 16 + n) * DDIM + hh * 32 + quad * 8);

  // swizzle read offsets (per-lane constants)
  const int kswz = (quad ^ (n & 7)) << 3;          // klo block; khi = kswz ^ 32
  int vswz[4];
#pragma unroll
  for (int st = 0; st < 4; ++st) vswz[st] = ((((st << 2) | quad) ^ n) << 2);

  f32x4 acc[2][4];
  float m[2] = {-1e30f, -1e30f}, ll[2] = {0.f, 0.f};
#pragma unroll
  for (int g = 0; g < 2; ++g)
#pragma unroll
    for (int t = 0; t < 4; ++t) acc[g][t] = (f32x4){0.f, 0.f, 0.f, 0.f};

  issue(0, 0);
  for (int c = 0; c < NC; ++c) {
    const int b = c & 1;
    __syncthreads();                      // drains chunk c's DMA; guards buffers
    if (c + 1 < NC) issue(c + 1, b ^ 1);  // in flight across entire compute phase

    // S' = K·Q^T
    f32x4 s[2][4];
#pragma unroll
    for (int st = 0; st < 4; ++st) {
      const f16* lkr = &lk[b][(st * 16 + n) * 64];
      const f16x8 klo = *(const f16x8*)(lkr + kswz);
      const f16x8 khi = *(const f16x8*)(lkr + (kswz ^ 32));
#pragma unroll
      for (int g = 0; g < 2; ++g) {
        f32x4 z = (f32x4){0.f, 0.f, 0.f, 0.f};
        z = MFMA32(klo, qf[g][0], z);
        s[g][st] = MFMA32(khi, qf[g][1], z);
      }
    }

    // per-lane online softmax; P packed directly as 16x16x16 B-fragments
    f16x4 pq[2][4];
#pragma unroll
    for (int g = 0; g < 2; ++g) {
      f32x4 mx;
#pragma unroll
      for (int r = 0; r < 4; ++r)
        mx[r] = fmaxf(fmaxf(s[g][0][r], s[g][1][r]), fmaxf(s[g][2][r], s[g][3][r]));
      float mloc = fmaxf(fmaxf(mx[0], mx[1]), fmaxf(mx[2], mx[3]));
      mloc = fmaxf(mloc, __shfl_xor(mloc, 16));
      mloc = fmaxf(mloc, __shfl_xor(mloc, 32));
      const float mnew = fmaxf(m[g], mloc);
      const float alpha = __builtin_amdgcn_exp2f(m[g] - mnew);
      m[g] = mnew;
      float psum = 0.f;
#pragma unroll
      for (int st = 0; st < 4; ++st) {
        f32x4 p;
#pragma unroll
        for (int r = 0; r < 4; ++r) p[r] = __builtin_amdgcn_exp2f(s[g][st][r] - mnew);
        psum += (p[0] + p[1]) + (p[2] + p[3]);
        pq[g][st] = cvt4(p[0], p[1], p[2], p[3]);
      }
      ll[g] = ll[g] * alpha + psum;
#pragma unroll
      for (int t = 0; t < 4; ++t) acc[g][t] *= alpha;
    }

    // O^T += V^T·P^T : A = V^T frag [m=d][k=key quad*4+j] (swizzled LDS read)
#pragma unroll
    for (int dt = 0; dt < 4; ++dt) {
      const f16* lvr = &lv[b][(dt * 16 + n) * 64];
#pragma unroll
      for (int st = 0; st < 4; ++st) {
        const f16x4 va = *(const f16x4*)(lvr + vswz[st]);
        acc[0][dt] = MFMA16(va, pq[0][st], acc[0][dt]);
        acc[1][dt] = MFMA16(va, pq[1][st], acc[1][dt]);
      }
    }
  }

  float lred[2];
#pragma unroll
  for (int g = 0; g < 2; ++g) {
    float l = ll[g];
    l += __shfl_xor(l, 16);
    l += __shfl_xor(l, 32);
    lred[g] = l;
  }

  if (NSPLIT == 1) {
#pragma unroll
    for (int g = 0; g < 2; ++g) {
      const float inv = 1.0f / lred[g];
      const int q = row0 + g * 16 + n;
#pragma unroll
      for (int t = 0; t < 4; ++t) {
        f32x4 o = acc[g][t];
#pragma unroll
        for (int r = 0; r < 4; ++r) o[r] *= inv;
        *(f32x4*)(outp + (size_t)q * DDIM + t * 16 + quad * 4) = o;
      }
    }
  } else {
#pragma unroll
    for (int g = 0; g < 2; ++g) {
      const int q = row0 + g * 16 + n;
#pragma unroll
      for (int t = 0; t < 4; ++t)
        *(f16x4*)(pacc + ((size_t)split * NROW + q) * DDIM + t * 16 + quad * 4) =
            cvt4(acc[g][t][0], acc[g][t][1], acc[g][t][2], acc[g][t][3]);
      if (quad == 0) {
        pm[split * NROW + q] = m[g];
        pl[split * NROW + q] = lred[g];
      }
    }
  }
}

// ---------------- attn split-K combine (f16 partials) ----------------
template <int NSPLIT>
__global__ __launch_bounds__(256) void combine_kernel(const f16* __restrict__ pacc,
                                                      const float* __restrict__ pm,
                                                      const float* __restrict__ pl,
                                                      float* __restrict__ out) {
  const int idx = blockIdx.x * 256 + threadIdx.x;  // NROW*16 units
  const int row = idx >> 4;
  const int c = (idx & 15) * 4;
  float mm = pm[row];
#pragma unroll
  for (int s = 1; s < NSPLIT; ++s) mm = fmaxf(mm, pm[s * NROW + row]);
  float L = 0.f;
  f32x4 o = (f32x4){0.f, 0.f, 0.f, 0.f};
#pragma unroll
  for (int s = 0; s < NSPLIT; ++s) {
    const float e = __builtin_amdgcn_exp2f(pm[s * NROW + row] - mm);
    L += pl[s * NROW + row] * e;
    const f16x4 a = *(const f16x4*)(pacc + ((size_t)s * NROW + row) * DDIM + c);
#pragma unroll
    for (int j = 0; j < 4; ++j) o[j] += (float)a[j] * e;
  }
  const float inv = 1.0f / L;
#pragma unroll
  for (int j = 0; j < 4; ++j) o[j] *= inv;
  *(f32x4*)(out + (size_t)row * DDIM + c) = o;
}

extern "C" void kernel_launch(void* const* d_in, const int* in_sizes, int n_in,
                              void* d_out, int out_size, void* d_ws, size_t ws_size,
                              hipStream_t stream) {
  const float* x  = (const float*)d_in[0];
  const float* Wq = (const float*)d_in[1];
  const float* bq = (const float*)d_in[2];
  const float* Wk = (const float*)d_in[3];
  const float* bk = (const float*)d_in[4];
  const float* Wv = (const float*)d_in[5];
  const float* bv = (const float*)d_in[6];
  float* out = (float*)d_out;

  f16* wf2 = (f16*)d_ws;                      // 3*64*1024 f16, mt-major slots
  f16* qs = wf2 + 3 * 65536;
  f16* ks = qs + (size_t)SEG;                 // block-swizzled
  f16* vc = ks + (size_t)SEG;                 // chunk-major tiles, swizzled
  f16* pacc = vc + (size_t)SEG;               // [NSPL][NROW][64] f16 attn partials
  float* pm = (float*)(pacc + (size_t)NSPL * SEG);
  float* pl = pm + (size_t)NSPL * NROW;
  const size_t need = (size_t)((char*)(pl + (size_t)NSPL * NROW) - (char*)d_ws);

  prep_w_kernel<<<dim3(96), dim3(256), 0, stream>>>(Wq, Wk, Wv, wf2);
  proj_kernel<<<dim3(NROW / 16), dim3(256), 0, stream>>>(x, wf2, bq, bk, bv, qs, ks, vc);

  if (ws_size >= need) {
    attn_kernel<NSPL><<<dim3(128 * NSPL), dim3(256), 0, stream>>>(qs, ks, vc, nullptr, pacc, pm, pl);
    combine_kernel<NSPL><<<dim3(NROW * 16 / 256), dim3(256), 0, stream>>>(pacc, pm, pl, out);
  } else {
    attn_kernel<1><<<dim3(128), dim3(256), 0, stream>>>(qs, ks, vc, out, nullptr, nullptr, nullptr);
  }
}